// Round 3
// baseline (1133.393 us; speedup 1.0000x reference)
//
#include <hip/hip_runtime.h>

// MaxUnpooling2D scatter-add — round 7: bucket == LDS window (CB=2^15), NT streams.
//
// R6 post-mortem: 1219 -> 1109 us. Remaining waste: (1) p4c read every
// coarse-bucket pair run TWICE (bit-15 filter discarded half of each read);
// (2) p3a's streaming reads share L2 with its partial write-combine lines.
//
// R7: CB_SHIFT 16 -> 15 so one coarse bucket IS one 128 KB apply window.
//   - p4c reads each pair exactly once (no filter, no sibling swizzle):
//     -268 MB reads.
//   - p3a now has 512 runs/block -> 2 MB/XCD open-line frontier (between
//     R6-good 1 MB and R4-bad 4 MB). All single-use streams (mask/updates
//     in p3a, pairs in p4c) use __builtin_nontemporal_load so they don't
//     evict the write-combine lines from L2.
//   - pre-commit: if p3a WRITE_SIZE >= 600 MB next round, revert to CB=16
//     keeping NT loads.
// Pipeline traffic ~2.0 -> ~1.46 GB.

typedef float floatx4 __attribute__((ext_vector_type(4)));
typedef int   intx4   __attribute__((ext_vector_type(4)));

constexpr int FLAT_IN   = 1 << 22;                 // 4,194,304
constexpr int N_ELEMS   = 8 * FLAT_IN;             // 33,554,432
constexpr int OUT_WIN   = 7 * FLAT_IN + (1 << 24); // 46,137,344
constexpr int OUT_TOTAL = 134217728;

constexpr int CB_SHIFT = 15;                  // coarse bucket: 32K floats = 128 KB
constexpr int NBC      = OUT_WIN >> CB_SHIFT; // 1408
constexpr int NBC_PAD  = 1536;                // 6*256 for scan kernels
constexpr int WIN_B    = 512;                 // buckets per p3a block window (2^24/2^15)

constexpr int APW      = 1 << CB_SHIFT;       // apply window = bucket = 32K floats
constexpr int NAP      = OUT_TOTAL >> CB_SHIFT; // 4096 (full output incl. tail)
constexpr int NAP_WIN  = NBC;                   // 1408 windows with pairs

constexpr int PBLOCK   = 1024;                // threads, partition kernels
constexpr int CHUNK    = 131072;              // elems per p1/p3a block
constexpr int NBLK     = N_ELEMS / CHUNK;     // 256
constexpr int ITERS    = CHUNK / (4 * PBLOCK);// 32
constexpr int SEGS     = 8;
constexpr int SEG_ROWS = NBLK / SEGS;         // 32

// ---- workspace layout (bytes) ----
constexpr size_t WS_PAIRS  = 0;                                     // int2[N_ELEMS] = 268,435,456
constexpr size_t WS_HISTC  = 268435456;                             // int[NBLK*NBC_PAD] = 1,572,864
constexpr size_t WS_SEGC   = WS_HISTC + (size_t)NBLK * NBC_PAD * 4; // int[SEGS*NBC_PAD]
constexpr size_t WS_BBC    = WS_SEGC + (size_t)SEGS * NBC_PAD * 4;  // int[NBC_PAD+1]
constexpr size_t WS_NEEDED = WS_BBC + (size_t)(NBC_PAD + 1) * 4;    // ~270.1 MB

// ---------------- K0: zero a float4 range (nontemporal) ----------------
__global__ __launch_bounds__(256) void zero_kernel(floatx4* __restrict__ p, int n4) {
  int i = blockIdx.x * 256 + threadIdx.x;
  int stride = gridDim.x * 256;
  floatx4 z = {0.f, 0.f, 0.f, 0.f};
  for (; i < n4; i += stride) __builtin_nontemporal_store(z, p + i);
}

// ---------------- K1: per-block coarse histogram ----------------
// Regular (cached) loads here: mask is re-read by p3a and 134 MB fits L3.
__global__ __launch_bounds__(PBLOCK) void p1_hist(const intx4* __restrict__ mask4,
                                                  int* __restrict__ hist_c) {
  __shared__ int cnt[WIN_B];  // bucket counts over this block's 2^24 window
  const int blk = blockIdx.x, tid = threadIdx.x;
  if (tid < WIN_B) cnt[tid] = 0;
  __syncthreads();
  const int base4 = blk * (CHUNK / 4);
  #pragma unroll 4
  for (int k = 0; k < ITERS; ++k) {
    intx4 m = mask4[base4 + k * PBLOCK + tid];
    atomicAdd(&cnt[m.x >> CB_SHIFT], 1);  // m.* < 2^24 -> index < 512
    atomicAdd(&cnt[m.y >> CB_SHIFT], 1);
    atomicAdd(&cnt[m.z >> CB_SHIFT], 1);
    atomicAdd(&cnt[m.w >> CB_SHIFT], 1);
  }
  __syncthreads();
  const int cb0 = ((blk * CHUNK) & ~(FLAT_IN - 1)) >> CB_SHIFT;  // multiple of 128
  for (int j = tid; j < NBC_PAD; j += PBLOCK) {
    int jj = j - cb0;
    hist_c[blk * NBC_PAD + j] = (jj >= 0 && jj < WIN_B) ? cnt[jj] : 0;
  }
}

// ---------------- K2a: segment sums over hist block rows ----------------
__global__ __launch_bounds__(256) void p2_segsum(const int* __restrict__ hist,
                                                 int* __restrict__ segsum) {
  int b = blockIdx.x * 256 + threadIdx.x;
  int seg = blockIdx.y;
  const int* p = hist + (size_t)(seg * SEG_ROWS) * NBC_PAD + b;
  int s = 0;
  #pragma unroll 4
  for (int k = 0; k < SEG_ROWS; ++k) s += p[(size_t)k * NBC_PAD];
  segsum[seg * NBC_PAD + b] = s;
}

// ---------------- K2b: bucket totals + exclusive scan -> bbase_c ----------
__global__ __launch_bounds__(256) void p2_scan_c(const int* __restrict__ segsum,
                                                 int* __restrict__ bbase) {
  __shared__ int tot[NBC_PAD];
  __shared__ int partial[256];
  const int t = threadIdx.x;
  for (int j = t; j < NBC_PAD; j += 256) {
    int s = 0;
    #pragma unroll
    for (int g = 0; g < SEGS; ++g) s += segsum[g * NBC_PAD + j];
    tot[j] = s;
  }
  __syncthreads();
  int local = 0;
  #pragma unroll
  for (int k = 0; k < NBC_PAD / 256; ++k) local += tot[t * (NBC_PAD / 256) + k];
  partial[t] = local;
  __syncthreads();
  for (int off = 1; off < 256; off <<= 1) {
    int tmp = (t >= off) ? partial[t - off] : 0;
    __syncthreads();
    partial[t] += tmp;
    __syncthreads();
  }
  int run = partial[t] - local;
  #pragma unroll
  for (int k = 0; k < NBC_PAD / 256; ++k) {
    int b = t * (NBC_PAD / 256) + k;
    bbase[b] = run;
    run += tot[b];
  }
  if (t == 255) bbase[NBC_PAD] = run;  // == N_ELEMS
}

// ---------------- K2c: expand hist in place to per-(block,cb) offsets ----
__global__ __launch_bounds__(256) void p2_expand(int* __restrict__ hist,
                                                 const int* __restrict__ segsum) {
  int b = blockIdx.x * 256 + threadIdx.x;
  int seg = blockIdx.y;
  int run = 0;
  for (int g = 0; g < seg; ++g) run += segsum[g * NBC_PAD + b];
  int* p = hist + (size_t)(seg * SEG_ROWS) * NBC_PAD + b;
  for (int k = 0; k < SEG_ROWS; ++k) {
    int v = p[(size_t)k * NBC_PAD];
    p[(size_t)k * NBC_PAD] = run;
    run += v;
  }
}

// ---------------- K3: coarse place (512 runs/block, NT streaming reads) ------
__global__ __launch_bounds__(PBLOCK) void p3a_place(const intx4* __restrict__ mask4,
                                                    const floatx4* __restrict__ upd4,
                                                    const int* __restrict__ hist_c,
                                                    const int* __restrict__ bbase_c,
                                                    int2* __restrict__ pout) {
  __shared__ int cnt[WIN_B];
  __shared__ int rowbase[WIN_B];
  const int blk = blockIdx.x, tid = threadIdx.x;
  const int boff = (blk * CHUNK) & ~(FLAT_IN - 1);
  const int cb0 = boff >> CB_SHIFT;
  if (tid < WIN_B) {
    cnt[tid] = 0;
    rowbase[tid] = bbase_c[cb0 + tid] + hist_c[blk * NBC_PAD + cb0 + tid];
  }
  __syncthreads();
  const int base4 = blk * (CHUNK / 4);
  #pragma unroll 2
  for (int k = 0; k < ITERS; ++k) {
    int j4 = base4 + k * PBLOCK + tid;
    intx4 m = __builtin_nontemporal_load(mask4 + j4);
    floatx4 u = __builtin_nontemporal_load(upd4 + j4);
    {
      int b = m.x >> CB_SHIFT; int r = atomicAdd(&cnt[b], 1);
      pout[rowbase[b] + r] = make_int2(m.x + boff, __float_as_int(u.x));
    }
    {
      int b = m.y >> CB_SHIFT; int r = atomicAdd(&cnt[b], 1);
      pout[rowbase[b] + r] = make_int2(m.y + boff, __float_as_int(u.y));
    }
    {
      int b = m.z >> CB_SHIFT; int r = atomicAdd(&cnt[b], 1);
      pout[rowbase[b] + r] = make_int2(m.z + boff, __float_as_int(u.z));
    }
    {
      int b = m.w >> CB_SHIFT; int r = atomicAdd(&cnt[b], 1);
      pout[rowbase[b] + r] = make_int2(m.w + boff, __float_as_int(u.w));
    }
  }
}

// ---------------- K4: apply one bucket == one 128 KB window -------------
// Block h covers out[h*APW, (h+1)*APW). For h < NAP_WIN it consumes pair
// run [bbase[h], bbase[h+1]) — every pair belongs (bucket == window).
// For h >= NAP_WIN (the tail) it streams zeros.
__global__ __launch_bounds__(1024) void p4c_apply(const int2* __restrict__ pairs,
                                                  const int* __restrict__ bbase,
                                                  float* __restrict__ out) {
  __shared__ float win[APW];  // 128 KB -> 1 block/CU
  const int tid = threadIdx.x;
  const int h = blockIdx.x;
  floatx4* w4 = (floatx4*)win;
  floatx4 z = {0.f, 0.f, 0.f, 0.f};
  #pragma unroll
  for (int k = 0; k < APW / 4096; ++k) w4[k * 1024 + tid] = z;  // 8 stores
  if (h < NAP_WIN) {
    __syncthreads();
    const int s = bbase[h], e = bbase[h + 1];
    const int s4 = (s + 1) & ~1;  // first even pair index (int4-aligned)
    if ((s & 1) && s < e && tid == 0) {
      int2 p = pairs[s];
      atomicAdd(&win[p.x & (APW - 1)], __int_as_float(p.y));
    }
    const int n2 = (e > s4) ? ((e - s4) >> 1) : 0;
    const intx4* pv = (const intx4*)(pairs + s4);
    for (int i = tid; i < n2; i += 1024) {
      intx4 q = __builtin_nontemporal_load(pv + i);
      atomicAdd(&win[q.x & (APW - 1)], __int_as_float(q.y));
      atomicAdd(&win[q.z & (APW - 1)], __int_as_float(q.w));
    }
    if ((e > s4) && ((e - s4) & 1) && tid == 0) {
      int2 p = pairs[e - 1];
      atomicAdd(&win[p.x & (APW - 1)], __int_as_float(p.y));
    }
    __syncthreads();
  }
  floatx4* o4 = (floatx4*)(out + (size_t)h * APW);
  #pragma unroll
  for (int k = 0; k < APW / 4096; ++k)
    __builtin_nontemporal_store(w4[k * 1024 + tid], o4 + k * 1024 + tid);
}

// ---------------- fallback: R1 atomic scatter ----------------
__global__ __launch_bounds__(256) void scatter_add4_kernel(
    const float4* __restrict__ upd4, const int4* __restrict__ msk4,
    float* __restrict__ out, int n4) {
  int j = blockIdx.x * blockDim.x + threadIdx.x;
  if (j >= n4) return;
  float4 u = upd4[j];
  int4 m = msk4[j];
  int base = (j * 4) & ~(FLAT_IN - 1);
  unsafeAtomicAdd(out + (base + m.x), u.x);
  unsafeAtomicAdd(out + (base + m.y), u.y);
  unsafeAtomicAdd(out + (base + m.z), u.z);
  unsafeAtomicAdd(out + (base + m.w), u.w);
}

extern "C" void kernel_launch(void* const* d_in, const int* in_sizes, int n_in,
                              void* d_out, int out_size, void* d_ws, size_t ws_size,
                              hipStream_t stream) {
  const float* updates = (const float*)d_in[0];
  const int*   mask    = (const int*)d_in[1];
  float*       out     = (float*)d_out;
  const int n = in_sizes[0];

  const bool fast = (n == N_ELEMS) && (out_size == OUT_TOTAL) && (ws_size >= WS_NEEDED);

  if (!fast) {
    int n4z = out_size / 4;
    zero_kernel<<<(n4z + 2047) / 2048, 256, 0, stream>>>((floatx4*)d_out, n4z);
    int n4 = n / 4;
    scatter_add4_kernel<<<(n4 + 255) / 256, 256, 0, stream>>>(
        (const float4*)updates, (const int4*)mask, out, n4);
    return;
  }

  char* ws = (char*)d_ws;
  int2* pairs   = (int2*)(ws + WS_PAIRS);
  int*  hist_c  = (int*)(ws + WS_HISTC);
  int*  segsum  = (int*)(ws + WS_SEGC);
  int*  bbase_c = (int*)(ws + WS_BBC);

  p1_hist<<<NBLK, PBLOCK, 0, stream>>>((const intx4*)mask, hist_c);
  p2_segsum<<<dim3(NBC_PAD / 256, SEGS), 256, 0, stream>>>(hist_c, segsum);
  p2_scan_c<<<1, 256, 0, stream>>>(segsum, bbase_c);
  p2_expand<<<dim3(NBC_PAD / 256, SEGS), 256, 0, stream>>>(hist_c, segsum);
  p3a_place<<<NBLK, PBLOCK, 0, stream>>>((const intx4*)mask, (const floatx4*)updates,
                                         hist_c, bbase_c, pairs);
  p4c_apply<<<NAP, 1024, 0, stream>>>(pairs, bbase_c, out);
}